// Round 10
// baseline (204.096 us; speedup 1.0000x reference)
//
#include <hip/hip_runtime.h>
#include <math.h>

// Problem constants
#define NSEQ 4096      // N
#define MFT  4096      // complex FFT length (even/odd pack of 2N=8192 real)
#define CHX  2048      // B*H*D channels of x
#define CHA  512       // H*D channels of a

// LDS bank swizzle (zero padding -> exactly 32768 B -> 5 blocks/CU).
// sf(i) = i ^ ((i>>4)&15): involution (self-inverse), keeps every exchange
// phase <=4-way bank aliasing on float2 (b64) accesses vs 32-way unswizzled.
static __device__ __forceinline__ int sf(int i) { return i ^ ((i >> 4) & 15); }

// ---------------------------------------------------------------- wave reduce
static __device__ __forceinline__ float wsum64(float v) {
    v += __shfl_xor(v, 1);
    v += __shfl_xor(v, 2);
    v += __shfl_xor(v, 4);
    v += __shfl_xor(v, 8);
    v += __shfl_xor(v, 16);
    v += __shfl_xor(v, 32);
    return v;
}

static __device__ __forceinline__ void ln_pair(float& x0, float& x1, float w, float b) {
    float mu0 = wsum64(x0) * (1.0f / 64.0f);
    float mu1 = wsum64(x1) * (1.0f / 64.0f);
    float d0 = x0 - mu0, d1 = x1 - mu1;
    float v0 = wsum64(d0 * d0) * (1.0f / 64.0f);
    float v1 = wsum64(d1 * d1) * (1.0f / 64.0f);
    x0 = d0 * rsqrtf(v0 + 1e-5f) * w + b;
    x1 = d1 * rsqrtf(v1 + 1e-5f) * w + b;
}

// ---------------------------------------------------------------- k_pre
// blocks [0,512):    RPE MLP, 2 positions/wave, writes aT[c][m] directly.
// blocks [512,2560): transpose x [32 slabs][4096 n][64 d] -> xT [32][64][4096]
// (measured R9: this ordering+split removed the R5 47us RPE straggler tail)
__global__ __launch_bounds__(256) void k_pre(
    const float* __restrict__ x,
    const float* __restrict__ pp_w, const float* __restrict__ pp_b,
    const float* __restrict__ ln_w, const float* __restrict__ ln_b,
    const float* __restrict__ lw,   const float* __restrict__ lb,
    const float* __restrict__ oln_w,const float* __restrict__ oln_b,
    const float* __restrict__ out_w,const float* __restrict__ out_b,
    float* __restrict__ xT, float* __restrict__ aT)
{
    __shared__ float tile[64][65];
    const int t = threadIdx.x;

    if (blockIdx.x >= 512) {                 // ---- x transpose (R=4096, C=64)
        const int bid = blockIdx.x - 512;    // 0..2047
        const int slab = bid >> 6;           // 0..31
        const int r0 = (bid & 63) * 64;
        const size_t base = (size_t)slab * 262144u;
        const int tc = t & 63, t4 = t >> 6;
        const float* s = x + base + (size_t)r0 * 64;
#pragma unroll
        for (int k = 0; k < 16; ++k) {
            int rr = t4 + k * 4;
            tile[rr][tc] = s[rr * 64 + tc];
        }
        __syncthreads();
        float* d = xT + base + r0;
#pragma unroll
        for (int k = 0; k < 16; ++k) {
            int cc = t4 + k * 4;
            d[(size_t)cc * 4096 + tc] = tile[tc][cc];
        }
        return;
    }

    // ---------------- RPE path (blocks 0..511), 2 positions per wave
    const int wave = t >> 6;
    const int lane = t & 63;
    const int mbase = ((int)blockIdx.x * 4 + wave) * 2;  // 0..4094, even
    const float m0 = (float)mbase, m1 = (float)(mbase + 1);

    float x0 = fmaf(m0, pp_w[lane], pp_b[lane]);
    float x1 = fmaf(m1, pp_w[lane], pp_b[lane]);

    for (int L = 0; L < 3; ++L) {
        ln_pair(x0, x1, ln_w[L * 64 + lane], ln_b[L * 64 + lane]);
        float r0 = fmaxf(x0, 0.0f), r1 = fmaxf(x1, 0.0f);
        float y0 = lb[L * 64 + lane], y1 = y0;
        const float* W = lw + L * 4096;
#pragma unroll 8
        for (int i = 0; i < 64; ++i) {
            float wi = W[i * 64 + lane];
            y0 = fmaf(__shfl(r0, i), wi, y0);
            y1 = fmaf(__shfl(r1, i), wi, y1);
        }
        x0 = y0; x1 = y1;
    }
    ln_pair(x0, x1, oln_w[lane], oln_b[lane]);
    float r0 = fmaxf(x0, 0.0f), r1 = fmaxf(x1, 0.0f);

    float acc0[8], acc1[8];
#pragma unroll
    for (int k = 0; k < 8; ++k) {
        float ob = out_b[k * 64 + lane];
        acc0[k] = ob; acc1[k] = ob;
    }
#pragma unroll 4
    for (int i = 0; i < 64; ++i) {
        float a0 = __shfl(r0, i);
        float a1 = __shfl(r1, i);
        const float* Wr = out_w + i * 512;
#pragma unroll
        for (int k = 0; k < 8; ++k) {
            float wv = Wr[k * 64 + lane];
            acc0[k] = fmaf(a0, wv, acc0[k]);
            acc1[k] = fmaf(a1, wv, acc1[k]);
        }
    }
    const float LOGG = -0.0010005003335835335f; // ln(0.999)
    float d0 = __expf(m0 * LOGG);               // gamma^m (m0==0 -> 1)
    float d1 = __expf(m1 * LOGG);
#pragma unroll
    for (int k = 0; k < 8; ++k) {
        int c = k * 64 + lane;
        float2 o;
        float v;
        v = acc0[k] * d0; o.x = v / (1.0f + __expf(-v));
        v = acc1[k] * d1; o.y = v / (1.0f + __expf(-v));
        *(float2*)(aT + (size_t)c * 4096 + mbase) = o;   // 8B-aligned (mbase even)
    }
}

// ---------------------------------------------------------------- out transpose
__global__ __launch_bounds__(256) void k_transpose(const float* __restrict__ src,
                                                   float* __restrict__ dst,
                                                   int R, int C) {
    __shared__ float tile[64][65];
    size_t slab = (size_t)blockIdx.z * (size_t)R * (size_t)C;
    int c0 = blockIdx.x * 64, r0 = blockIdx.y * 64;
    int t = threadIdx.x;
    int tc = t & 63, t4 = t >> 6;
    const float* s = src + slab + (size_t)r0 * C + c0;
#pragma unroll
    for (int k = 0; k < 16; ++k) {
        int rr = t4 + k * 4;
        tile[rr][tc] = s[(size_t)rr * C + tc];
    }
    __syncthreads();
    float* d = dst + slab + (size_t)c0 * R + r0;
#pragma unroll
    for (int k = 0; k < 16; ++k) {
        int cc = t4 + k * 4;
        d[(size_t)cc * R + tc] = tile[tc][cc];
    }
}

// ---------------------------------------------------------------- register FFT
static __device__ __forceinline__ void cmulrw(float& r, float& i, float wr, float wi) {
    float t = r * wr - i * wi;
    i = r * wi + i * wr;
    r = t;
}

template<bool INV>
static __device__ __forceinline__ void dft4(float& ar, float& ai, float& br, float& bi,
                                            float& cr, float& ci, float& dr, float& di) {
    float t0r = ar + cr, t0i = ai + ci, t1r = ar - cr, t1i = ai - ci;
    float t2r = br + dr, t2i = bi + di, t3r = br - dr, t3i = bi - di;
    float u3r = INV ? -t3i : t3i;
    float u3i = INV ?  t3r : -t3r;
    ar = t0r + t2r; ai = t0i + t2i;
    br = t1r + u3r; bi = t1i + u3i;
    cr = t0r - t2r; ci = t0i - t2i;
    dr = t1r - u3r; di = t1i - u3i;
}

template<bool INV>
static __device__ __forceinline__ void radix16(float (&vr)[16], float (&vi)[16]) {
    const float C1 = 0.92387953251128674f;  // cos(pi/8)
    const float S1 = 0.38268343236508978f;  // sin(pi/8)
    const float R2 = 0.70710678118654752f;
    const float SG = INV ? 1.0f : -1.0f;
#pragma unroll
    for (int na = 0; na < 4; ++na)
        dft4<INV>(vr[na], vi[na], vr[na + 4], vi[na + 4],
                  vr[na + 8], vi[na + 8], vr[na + 12], vi[na + 12]);
    cmulrw(vr[5],  vi[5],   C1, SG * S1);   // m=1
    cmulrw(vr[9],  vi[9],   R2, SG * R2);   // m=2
    cmulrw(vr[13], vi[13],  S1, SG * C1);   // m=3
    cmulrw(vr[6],  vi[6],   R2, SG * R2);   // m=2
    {   // m=4: fwd *(0,-1); inv *(0,+1)
        float tmp = vr[10];
        if (INV) { vr[10] = -vi[10]; vi[10] =  tmp; }
        else     { vr[10] =  vi[10]; vi[10] = -tmp; }
    }
    cmulrw(vr[14], vi[14], -R2, SG * R2);   // m=6
    cmulrw(vr[7],  vi[7],   S1, SG * C1);   // m=3
    cmulrw(vr[11], vi[11], -R2, SG * R2);   // m=6
    cmulrw(vr[15], vi[15], -C1, -SG * S1);  // m=9
    float yr[16], yi[16];
#pragma unroll
    for (int kb = 0; kb < 4; ++kb) {
        float ar = vr[4*kb+0], ai = vi[4*kb+0], br = vr[4*kb+1], bi = vi[4*kb+1];
        float cr = vr[4*kb+2], ci = vi[4*kb+2], dr = vr[4*kb+3], di = vi[4*kb+3];
        dft4<INV>(ar, ai, br, bi, cr, ci, dr, di);
        yr[kb]      = ar; yi[kb]      = ai;
        yr[kb + 4]  = br; yi[kb + 4]  = bi;
        yr[kb + 8]  = cr; yi[kb + 8]  = ci;
        yr[kb + 12] = dr; yi[kb + 12] = di;
    }
#pragma unroll
    for (int k = 0; k < 16; ++k) { vr[k] = yr[k]; vi[k] = yi[k]; }
}

// Full 4096-pt FFT, 16^3. In: thread t holds x[t+256*n3] in slot n3.
// Out: thread t holds X[t+256*k1] in slot k1. Twiddles on the fly.
template<bool INV>
static __device__ __forceinline__ void fft4096_reg(float (&vr)[16], float (&vi)[16],
                                                   float2* __restrict__ lds, int t)
{
    radix16<INV>(vr, vi);                       // over n3 -> k3
    __syncthreads();
#pragma unroll
    for (int k3 = 0; k3 < 16; ++k3)
        lds[sf(t + (k3 << 8))] = make_float2(vr[k3], vi[k3]);
    __syncthreads();
    {   // thread t = n1 + 16*k3 ; read over n2, twiddle W256^(n2*k3)
        int n1 = t & 15, k3 = t >> 4;
        float ang = (float)k3 * (1.0f / 128.0f);
        float wr = cospif(ang);
        float wi = INV ? sinpif(ang) : -sinpif(ang);
        float cr = 1.0f, ci = 0.0f;
#pragma unroll
        for (int n2 = 0; n2 < 16; ++n2) {
            float2 v = lds[sf(n1 + (n2 << 4) + (k3 << 8))];
            vr[n2] = v.x * cr - v.y * ci;
            vi[n2] = v.x * ci + v.y * cr;
            float ncr = cr * wr - ci * wi;
            ci = cr * wi + ci * wr; cr = ncr;
        }
    }
    radix16<INV>(vr, vi);                       // over n2 -> k2
    __syncthreads();
#pragma unroll
    for (int k2 = 0; k2 < 16; ++k2)
        lds[sf(t + (k2 << 8))] = make_float2(vr[k2], vi[k2]);
    __syncthreads();
    {   // thread t = k3 + 16*k2 ; read 16 consecutive, twiddle W4096^(n1*t)
        float ang = (float)t * (1.0f / 2048.0f);
        float wr = cospif(ang);
        float wi = INV ? sinpif(ang) : -sinpif(ang);
        float cr = 1.0f, ci = 0.0f;
#pragma unroll
        for (int n1 = 0; n1 < 16; ++n1) {
            float2 v = lds[sf((t << 4) + n1)];
            vr[n1] = v.x * cr - v.y * ci;
            vi[n1] = v.x * ci + v.y * cr;
            float ncr = cr * wr - ci * wi;
            ci = cr * wi + ci * wr; cr = ncr;
        }
    }
    radix16<INV>(vr, vi);                       // over n1 -> k1
}

// ---------------------------------------------------------------- forward FFT (a-side)
// blocks [0,512): FFT one a-channel, then UNPACK to true 8192-bin rfft pairs:
//   ZaU[ca][2f]   = A[f]        (f = 0..2048)
//   ZaU[ca][2f+1] = A[f+4096]
// stored as one float4 per bin (coalesced; conv loads 1 float4, no unpack).
// block 512: fills ctab[f] = (cos(pi f/4096), sin(pi f/4096)), f=0..2048.
#define ZAROW 4100     // float2 per a-row (2*2049, padded to float4 alignment)
__global__ __launch_bounds__(256, 5) void k_fft_fwd(const float2* __restrict__ src,
                                                    float2* __restrict__ ZaU,
                                                    float2* __restrict__ ctab) {
    __shared__ float2 lds[4096];
    const int t = threadIdx.x;
    if (blockIdx.x == CHA) {          // ---- twiddle table
        for (int f = t; f <= 2048; f += 256) {
            float fr = (float)f * (1.0f / 4096.0f);
            ctab[f] = make_float2(cospif(fr), sinpif(fr));
        }
        return;
    }
    const float2* s = src + (size_t)blockIdx.x * 2048;
    float vr[16], vi[16];
#pragma unroll
    for (int n3 = 0; n3 < 8; ++n3) {
        float2 v = s[t + (n3 << 8)];
        vr[n3] = v.x; vi[n3] = v.y;
    }
#pragma unroll
    for (int n3 = 8; n3 < 16; ++n3) { vr[n3] = 0.0f; vi[n3] = 0.0f; }
    fft4096_reg<false>(vr, vi, lds, t);

    __syncthreads();
#pragma unroll
    for (int k1 = 0; k1 < 16; ++k1)
        lds[sf(t + (k1 << 8))] = make_float2(vr[k1], vi[k1]);
    __syncthreads();

    float4* zu = (float4*)(ZaU + (size_t)blockIdx.x * ZAROW);
    for (int f = t; f <= 2048; f += 256) {
        const int fm = (4096 - f) & 4095;
        float2 Zf = lds[sf(f)], Zm = lds[sf(fm)];
        float Ear = 0.5f * (Zf.x + Zm.x), Eai = 0.5f * (Zf.y - Zm.y);
        float Oar = 0.5f * (Zf.y + Zm.y), Oai = 0.5f * (Zm.x - Zf.x);
        float fr = (float)f * (1.0f / 4096.0f);
        float cp = cospif(fr), sp = sinpif(fr);
        float tOr = cp * Oar + sp * Oai, tOi = cp * Oai - sp * Oar;
        float4 o;
        o.x = Ear + tOr; o.y = Eai + tOi;     // A[f]
        o.z = Ear - tOr; o.w = Eai - tOi;     // A[f+4096]
        zu[f] = o;
    }
}

// ---------------------------------------------------------------- fused FFT(x)+conv+iFFT
__global__ __launch_bounds__(256, 5) void k_fft_conv_inv(const float2* __restrict__ xrow,
                                                         const float2* __restrict__ ZaU,
                                                         const float2* __restrict__ ctab,
                                                         float* __restrict__ yT) {
    __shared__ float2 lds[4096];     // 32768 B exactly -> 5 blocks/CU
    const int t = threadIdx.x;
    const int bc = blockIdx.x;          // 0..2047
    const int ca = bc & 511;            // h*64 + d
    const float2* s = xrow + (size_t)bc * 2048;
    float vr[16], vi[16];
#pragma unroll
    for (int n3 = 0; n3 < 8; ++n3) {
        float2 v = s[t + (n3 << 8)];
        vr[n3] = v.x; vi[n3] = v.y;
    }
#pragma unroll
    for (int n3 = 8; n3 < 16; ++n3) { vr[n3] = 0.0f; vi[n3] = 0.0f; }
    fft4096_reg<false>(vr, vi, lds, t);            // X[t + 256*k1] in regs

    __syncthreads();                                // last exchange readers done
#pragma unroll
    for (int k1 = 0; k1 < 16; ++k1)                 // stage spectrum to LDS
        lds[sf(t + (k1 << 8))] = make_float2(vr[k1], vi[k1]);
    __syncthreads();

    const float4* zu = (const float4*)(ZaU + (size_t)ca * ZAROW);
    // Each (f, 4096-f) pair owned by exactly one thread -> in-place safe.
    for (int f = t; f <= 2048; f += 256) {
        const int fm = (4096 - f) & 4095;
        float2 Xf = lds[sf(f)], Xm = lds[sf(fm)];
        float4 A = zu[f];                   // (A[f], A[f+4096]) pre-unpacked
        float2 ct = ctab[f];                // (cos, sin)(pi f / 4096)
        float cp = ct.x, sp = ct.y;
        // unpack X to true bins
        float Exr = 0.5f * (Xf.x + Xm.x), Exi = 0.5f * (Xf.y - Xm.y);
        float Oxr = 0.5f * (Xf.y + Xm.y), Oxi = 0.5f * (Xm.x - Xf.x);
        float tOxr = cp * Oxr + sp * Oxi, tOxi = cp * Oxi - sp * Oxr;
        float Xpr = Exr + tOxr, Xpi = Exi + tOxi;   // X8192[f]
        float Xqr = Exr - tOxr, Xqi = Exi - tOxi;   // X8192[f+4096]
        // multiply
        float Pr = Xpr * A.x - Xpi * A.y, Pi = Xpr * A.y + Xpi * A.x;
        float Qr = Xqr * A.z - Xqi * A.w, Qi = Xqr * A.w + Xqi * A.z;
        // repack: Ye = (P+Q)/2 ; Yo = conj(t)*(P-Q)/2 ; W = Ye + i*Yo
        float Sr = 0.5f * (Pr + Qr), Si = 0.5f * (Pi + Qi);
        float Dr = 0.5f * (Pr - Qr), Di = 0.5f * (Pi - Qi);
        float Cr = cp * Dr - sp * Di, Ci = cp * Di + sp * Dr;
        lds[sf(f)]  = make_float2(Sr - Ci, Si + Cr);
        lds[sf(fm)] = make_float2(Sr + Ci, Cr - Si);  // W[-f] = conj(Ye - i*Yo)
    }
    __syncthreads();
#pragma unroll
    for (int n3 = 0; n3 < 16; ++n3) {               // load W for inverse FFT
        float2 v = lds[sf(t + (n3 << 8))];
        vr[n3] = v.x; vi[n3] = v.y;
    }
    fft4096_reg<true>(vr, vi, lds, t);              // y packed in regs

    const float sc = 1.0f / 4096.0f;
    float2* dst = (float2*)yT + (size_t)bc * 2048;
#pragma unroll
    for (int k1 = 0; k1 < 8; ++k1) {                // first 2048 cplx = 4096 reals
        int idx = t + (k1 << 8);
        dst[idx] = make_float2(vr[k1] * sc, vi[k1] * sc);
    }
}

// ---------------------------------------------------------------- launch
extern "C" void kernel_launch(void* const* d_in, const int* in_sizes, int n_in,
                              void* d_out, int out_size, void* d_ws, size_t ws_size,
                              hipStream_t stream) {
    const float* x     = (const float*)d_in[0];
    const float* pp_w  = (const float*)d_in[1];
    const float* pp_b  = (const float*)d_in[2];
    const float* ln_w  = (const float*)d_in[3];
    const float* ln_b  = (const float*)d_in[4];
    const float* lw    = (const float*)d_in[5];
    const float* lb    = (const float*)d_in[6];
    const float* oln_w = (const float*)d_in[7];
    const float* oln_b = (const float*)d_in[8];
    const float* out_w = (const float*)d_in[9];
    const float* out_b = (const float*)d_in[10];
    float* out = (float*)d_out;
    char* ws = (char*)d_ws;

    // ws layout (bytes), total ~58.8 MB:
    //   xT   @ 0        : 2048x4096 f32  (33.55 MB) x channel-major; aliased by yT
    //   aT   @ 33554432 : 512x4096  f32  ( 8.39 MB) silu(decay*rpe), channel-major
    //   ZaU  @ 41943040 : 512x4100  cplx (16.79 MB) UNPACKED a-spectra (float4/bin)
    //   ctab @ 58736640 : 2049      cplx (16 KB)    conv twiddles
    float*  xT   = (float*)(ws);
    float*  aT   = (float*)(ws + 33554432u);
    float2* ZaU  = (float2*)(ws + 41943040u);
    float2* ctab = (float2*)(ws + 58736640u);
    float*  yT   = xT;   // xT dead after the fused kernel consumes it

    // 1: RPE->aT (blocks 0..511) + x-transpose (blocks 512..2559)
    k_pre<<<2560, 256, 0, stream>>>(x, pp_w, pp_b, ln_w, ln_b, lw, lb,
                                    oln_w, oln_b, out_w, out_b, xT, aT);
    // 2: forward FFT + unpack of a-channels (+ ctab fill in block 512)
    k_fft_fwd<<<CHA + 1, 256, 0, stream>>>((const float2*)aT, ZaU, ctab);
    // 3: fused FFT(x) * A -> iFFT -> yT
    k_fft_conv_inv<<<CHX, 256, 0, stream>>>((const float2*)xT, ZaU, ctab, yT);
    // 4: yT [32][64 d][4096 n] -> out [32][4096 n][64 d]
    k_transpose<<<dim3(64, 1, 32), 256, 0, stream>>>(yT, out, 64, 4096);
}